// Round 1
// baseline (1744.783 us; speedup 1.0000x reference)
//
#include <hip/hip_runtime.h>

// B=128, T=48, I=128, H=512. Sequential 48-step attention+GRU scan.
// R6: "everything stationary" restructure.
//  - ph1 col-sliced MFMA as before, but gate (gh) columns are owned by the
//    same block that consumes them in ph3 -> gh goes through LDS, not global.
//  - ph2 row-owned, w2h/dx/xin preloaded to LDS once; only reads the 2KB w1
//    row from global.
//  - ph3 col-sliced: WcT slice (131x96 cols, f32) lives in LDS; h state in
//    registers; exchange is y[16,131] (8.4KB/group).
//  - Exchanges: writes stay relaxed agent-scope (write-through, acked at MALL
//    before flag). Reads are PLAIN cached loads after an agent acquire fence
//    (buffer_inv) -> co-XCD blocks share one MALL fetch via L2. Correct
//    regardless of XCD placement; placement only affects speed.
//  - 3 light barriers/step (h, w1, y).

typedef _Float16 half8 __attribute__((ext_vector_type(8)));
typedef _Float16 h2v  __attribute__((ext_vector_type(2)));
typedef float    f32x4 __attribute__((ext_vector_type(4)));

// ---------------- ws layout (bytes) ----------------
#define OFF_BAR   0u          // 128 flags * 128B (zeroed by prep)
#define OFF_BZ    32768u      // 2048 f32 : [b1 ; b_hh]
#define OFF_BC    40960u      // 1536 f32 : W_ih@b4 + b_ih
#define OFF_WZ    65536u      // 2048*512 f16 : [W1 ; W_hh] row-major
#define OFF_WCT   2162688u    // 131*1536 f16 : (W_ih@W4)^T, k-major
#define OFF_W2H   3178496u    // 128*48*512 f16 : dx@W2^T + b2
#define OFF_HGH   9732096u    // 128*512 f16 : h (cross-block exchange)
#define OFF_ZG    9863168u    // 128*512 f32 : w1 exchange (256 KB)
#define OFF_Y     10125312u   // 128*132 f32 : y exchange (67.6 KB)

__device__ __forceinline__ float fexp2(float x) { return __builtin_amdgcn_exp2f(x); }
__device__ __forceinline__ float frcp(float x)  { return __builtin_amdgcn_rcpf(x); }
__device__ __forceinline__ float fast_tanh(float x) {
  x = fminf(fmaxf(x, -15.f), 15.f);
  float e = fexp2(x * 2.8853900817779268f);   // exp(2x)
  return (e - 1.f) * frcp(e + 1.f);
}
__device__ __forceinline__ float fast_sigmoid(float x) {
  x = fminf(fmaxf(x, -30.f), 30.f);
  float e = fexp2(x * 1.4426950408889634f);   // exp(x)
  return e * frcp(e + 1.f);
}

// ---- coherent (agent-scope, write-through) stores ----
__device__ __forceinline__ void st_f32(float* p, float v) {
  __hip_atomic_store(p, v, __ATOMIC_RELAXED, __HIP_MEMORY_SCOPE_AGENT);
}
__device__ __forceinline__ void st_u32(unsigned int* p, unsigned int v) {
  __hip_atomic_store(p, v, __ATOMIC_RELAXED, __HIP_MEMORY_SCOPE_AGENT);
}
union H4 { unsigned long long u; _Float16 h[4]; };
union HU { unsigned int u; h2v h; };

// Acquire fence at agent scope: lowers to buffer_inv (L1+L2 invalidate).
// After this, PLAIN loads observe all write-through stores that were acked at
// the MALL before the producer's flag store. Dirty lines are preserved.
__device__ __forceinline__ void acq_fence() {
  __builtin_amdgcn_fence(__ATOMIC_ACQUIRE, "agent");
  __asm__ __volatile__("" ::: "memory");
}

// All-relaxed flag barrier (unchanged from R5). __syncthreads() drains vmcnt
// so all prior write-through stores are ACKED at the MALL before the flag
// store issues; pollers load flags with agent-scope (bypass) loads.
__device__ __forceinline__ void flag_barrier(unsigned int* flags, int myIdx,
                                             int base16, unsigned int target,
                                             int tid, int lane, int wv) {
  __syncthreads();   // drains vmcnt: all sc stores acked at coherence point
  if (tid == 0)
    __hip_atomic_store(flags + myIdx * 32, target, __ATOMIC_RELAXED,
                       __HIP_MEMORY_SCOPE_AGENT);
  if (wv == 0) {
    unsigned int* fp = flags + (base16 + (lane & 15)) * 32;
    for (;;) {
      unsigned int v = (lane < 16)
        ? __hip_atomic_load(fp, __ATOMIC_RELAXED, __HIP_MEMORY_SCOPE_AGENT)
        : target;
      if ((__ballot(v < target) & 0xFFFFull) == 0) break;
      __builtin_amdgcn_s_sleep(1);
    }
    __asm__ __volatile__("" ::: "memory");
  }
  __syncthreads();
}

// ---------------- fused prep kernel (grid 322 x 256) ----------------
__global__ __launch_bounds__(256) void prep_all(
    const float* __restrict__ dx, const float* __restrict__ h0,
    const float* __restrict__ W1, const float* __restrict__ Whh,
    const float* __restrict__ b1, const float* __restrict__ bhh,
    const float* __restrict__ Wih, const float* __restrict__ W4,
    const float* __restrict__ b4, const float* __restrict__ bih,
    const float* __restrict__ W2, const float* __restrict__ b2,
    const float* __restrict__ bfc,
    _Float16* __restrict__ hgh,
    _Float16* __restrict__ Wzh, float* __restrict__ bz,
    float* __restrict__ bc, _Float16* __restrict__ WcT,
    _Float16* __restrict__ w2h, unsigned int* __restrict__ bar,
    float* __restrict__ out)
{
  __shared__ __align__(16) char smem[58368];
  const int bid = blockIdx.x;
  const int tid = threadIdx.x;
  const int lane = tid & 63, wv = tid >> 6;

  if (bid == 0) {                       // zero flag region (8192 u32)
    for (int i = tid; i < 8192; i += 256) bar[i] = 0u;
  } else if (bid == 1) {                // bz + out(re) init
    for (int n = tid; n < 2048; n += 256)
      bz[n] = (n < 512) ? b1[n] : bhh[n - 512];
    if (tid < 128) out[tid] = bfc[0];
  } else if (bid < 18) {                // bc: 16 blocks x 96 rows, wave/row
    const int o0 = (bid - 2) * 96 + wv * 24;
    for (int it = 0; it < 24; ++it) {
      const int row = o0 + it;
      const float* r = Wih + row * 512 + lane * 8;
      float s = 0.f;
#pragma unroll
      for (int u = 0; u < 8; ++u) s += r[u] * b4[lane * 8 + u];
#pragma unroll
      for (int off = 32; off >= 1; off >>= 1) s += __shfl_xor(s, off);
      if (lane == 0) bc[row] = bih[row] + s;
    }
  } else if (bid < 34) {                // hgh init (f16 copy of h0)
    const int i0 = (bid - 18) * 4096 + tid * 16;
#pragma unroll
    for (int u = 0; u < 4; ++u) {
      float4 v = *(const float4*)(h0 + i0 + u * 4);
      H4 p; p.h[0] = (_Float16)v.x; p.h[1] = (_Float16)v.y;
      p.h[2] = (_Float16)v.z; p.h[3] = (_Float16)v.w;
      *(unsigned long long*)(hgh + i0 + u * 4) = p.u;
    }
  } else if (bid < 98) {                // Wzh = f16([W1;Whh]) flat copy
    const int i0 = (bid - 34) * 16384 + tid * 64;
#pragma unroll 4
    for (int u = 0; u < 16; ++u) {
      const int i = i0 + u * 4;
      const float* src = (i < 262144) ? (W1 + i) : (Whh + i - 262144);
      float4 v = *(const float4*)src;
      H4 p; p.h[0] = (_Float16)v.x; p.h[1] = (_Float16)v.y;
      p.h[2] = (_Float16)v.z; p.h[3] = (_Float16)v.w;
      *(unsigned long long*)(Wzh + i) = p.u;
    }
  } else if (bid < 194) {               // WcT[k][o] = (Wih@W4)[o][k]
    float* wih = (float*)smem;                 // 16*66
    float* w4s = (float*)(smem + 4224);        // 64*132
    const int o0 = (bid - 98) * 16;
    const int k = tid;
    float acc[16];
#pragma unroll
    for (int i = 0; i < 16; ++i) acc[i] = 0.f;
    for (int jc = 0; jc < 512; jc += 64) {
      __syncthreads();
      for (int idx = tid; idx < 16 * 64; idx += 256) {
        int oo = idx >> 6, jj = idx & 63;
        wih[oo * 66 + jj] = Wih[(o0 + oo) * 512 + jc + jj];
      }
      for (int idx = tid; idx < 64 * 131; idx += 256) {
        int r = idx / 131, c = idx - r * 131;
        w4s[r * 132 + c] = W4[(jc + r) * 131 + c];
      }
      __syncthreads();
      if (k < 131) {
        for (int jj = 0; jj < 64; ++jj) {
          float w4v = w4s[jj * 132 + k];
#pragma unroll
          for (int oo = 0; oo < 16; ++oo) acc[oo] += wih[oo * 66 + jj] * w4v;
        }
      }
    }
    if (k < 131) {
#pragma unroll
      for (int oo = 0; oo < 16; ++oo)
        WcT[k * 1536 + o0 + oo] = (_Float16)acc[oo];
    }
  } else {                              // w2h: 128 blocks, one batch row each
    float* dxa = (float*)smem;                 // 48*128 f32
    _Float16* w2t = (_Float16*)(smem + 24576); // 128*132 f16
    const int b = bid - 194;
    for (int idx = tid; idx < 48 * 128; idx += 256)
      dxa[idx] = dx[b * 6144 + idx];
    for (int hc = 0; hc < 4; ++hc) {
      __syncthreads();
      for (int idx = tid; idx < 128 * 128; idx += 256) {
        int hl = idx >> 7, i = idx & 127;
        w2t[i * 132 + hl] = (_Float16)W2[(hc * 128 + hl) * 128 + i];
      }
      __syncthreads();
      const int hh = tid & 127;
      const int tq = tid >> 7;
      const float b2v = b2[hc * 128 + hh];
      for (int tt = tq * 24; tt < tq * 24 + 24; ++tt) {
        float acc = b2v;
#pragma unroll 4
        for (int i = 0; i < 128; ++i)
          acc += dxa[tt * 128 + i] * (float)w2t[i * 132 + hh];
        w2h[(b * 48 + tt) * 512 + hc * 128 + hh] = (_Float16)acc;
      }
    }
  }
}

// ---------------- main persistent scan kernel ----------------
__global__ __launch_bounds__(256, 1) void decoder_main(
    const float* __restrict__ dx, const float* __restrict__ xin,
    const float* __restrict__ h0,
    const float* __restrict__ W3, const float* __restrict__ b3,
    const float* __restrict__ Wfc,
    const _Float16* __restrict__ Wzh, const float* __restrict__ bz,
    const _Float16* __restrict__ WcT, const float* __restrict__ bc,
    const _Float16* __restrict__ w2h,
    _Float16* __restrict__ hgh, float* __restrict__ zg,
    float* __restrict__ yg,
    unsigned int* __restrict__ bar, float* __restrict__ out)
{
  const int tid  = threadIdx.x;
  const int lane = tid & 63;
  const int wv   = tid >> 6;
  const int bid  = blockIdx.x;
  const int grp  = bid & 7;      // XCD-local heuristic (perf only)
  const int mem  = bid >> 3;     // 0..15 : which member of the group
  const int b0   = grp * 16;     // first batch row of this group
  const int myrow = b0 + mem;    // this block's ph2 row
  const int myIdx = grp * 16 + mem;
  const int base16 = grp * 16;
  unsigned int sync_no = 0;

  // ---- LDS (152.9 KiB total) ----
  __shared__ _Float16 w2lds[48 * 512];   // 49152 B : w2h[myrow]
  __shared__ float dxlds[48 * 128];      // 24576 B : dx[myrow]
  __shared__ float wctlds[131 * 128];    // 67072 B : WcT slice, f32 [k][hp][8]
  __shared__ float ylds[16 * 132];       //  8448 B : staged y of all 16 rows
  __shared__ float ghlds[3 * 16 * 32];   //  6144 B : gh[gate][row][hcol32]
  __shared__ float xlds[48 * 4];         //   768 B : xin[myrow], padded
  __shared__ float es[48];
  __shared__ float asx[48];

  const int m = lane & 15, q = lane >> 4;

  // ---- ph1 persistent weights: 2 col-tiles of 16 per wave (128 VGPRs) ----
  // column assignment: wave 0 -> w1 cols [mem*32,+32); wave g(1..3) -> gate
  // g-1 cols [g*512 + mem*32, +32). ncol = wv*512 + mem*32 + t*16 + m.
  half8 wzf[2][16];
  float bzv[2];
#pragma unroll
  for (int t = 0; t < 2; ++t) {
    const int ncol = wv * 512 + mem * 32 + t * 16 + m;
    const _Float16* wrow = Wzh + ncol * 512 + q * 8;
#pragma unroll
    for (int ks = 0; ks < 16; ++ks) wzf[t][ks] = *(const half8*)(wrow + ks * 32);
    bzv[t] = bz[ncol];
  }
  float w3r[8];
#pragma unroll
  for (int u = 0; u < 8; ++u) w3r[u] = W3[lane * 8 + u];
  const float b3v = b3[0];

  // ---- ph3 per-thread state: thread owns (row3, h-cols gc, gc+1) ----
  const int row3 = tid >> 4, hp3 = tid & 15;
  const int gc = mem * 32 + 2 * hp3;            // global h-col
  const float bcR0 = bc[gc],        bcR1 = bc[gc + 1];
  const float bcZ0 = bc[512 + gc],  bcZ1 = bc[513 + gc];
  const float bcN0 = bc[1024 + gc], bcN1 = bc[1025 + gc];
  const float wfcA = Wfc[gc], wfcB = Wfc[gc + 1];
  float hA = h0[(b0 + row3) * 512 + gc];        // fp32 h master in registers
  float hB = h0[(b0 + row3) * 512 + gc + 1];

  // ---- one-time LDS preload ----
  {
    const half8* w2src = (const half8*)(w2h + myrow * 48 * 512);
    half8* w2dst = (half8*)w2lds;
    for (int i = tid; i < 3072; i += 256) w2dst[i] = w2src[i];
    const float4* dxsrc = (const float4*)(dx + myrow * 6144);
    float4* dxdst = (float4*)dxlds;
    for (int i = tid; i < 1536; i += 256) dxdst[i] = dxsrc[i];
    for (int i = tid; i < 131 * 16; i += 256) {
      const int k = i >> 4, hp = i & 15;
      const _Float16* wr = WcT + k * 1536 + mem * 32 + 2 * hp;
      float4 lo = {(float)wr[0], (float)wr[512], (float)wr[1024], 0.f};
      float4 hi = {(float)wr[1], (float)wr[513], (float)wr[1025], 0.f};
      *(float4*)(wctlds + k * 128 + hp * 8)     = lo;
      *(float4*)(wctlds + k * 128 + hp * 8 + 4) = hi;
    }
    for (int i = tid; i < 144; i += 256) {
      const int t = i / 3, j = i - t * 3;
      xlds[t * 4 + j] = xin[myrow * 144 + i];
    }
  }
  __syncthreads();

  for (int step = 0; step < 48; ++step) {
    // ---- ph1: z-slice = h @ [W1|W_hh]^T + bz (MFMA, weights in regs).
    //      w1 cols -> global zg ; gate cols -> LDS (consumed locally in ph3).
    {
      half8 af[16];
      const _Float16* hrow = hgh + (b0 + m) * 512 + q * 8;
#pragma unroll
      for (int ks = 0; ks < 16; ++ks) af[ks] = *(const half8*)(hrow + ks * 32);
#pragma unroll
      for (int t = 0; t < 2; ++t) {
        f32x4 acc = {bzv[t], bzv[t], bzv[t], bzv[t]};
#pragma unroll
        for (int ks = 0; ks < 16; ++ks)
          acc = __builtin_amdgcn_mfma_f32_16x16x32_f16(af[ks], wzf[t][ks], acc, 0, 0, 0);
        if (wv == 0) {
#pragma unroll
          for (int r = 0; r < 4; ++r)
            st_f32(&zg[(b0 + q * 4 + r) * 512 + mem * 32 + t * 16 + m], acc[r]);
        } else {
#pragma unroll
          for (int r = 0; r < 4; ++r)
            ghlds[(wv - 1) * 512 + (q * 4 + r) * 32 + t * 16 + m] = acc[r];
        }
      }
    }
    ++sync_no; flag_barrier(bar, myIdx, base16, sync_no, tid, lane, wv);
    acq_fence();

    // ---- ph2: e -> softmax -> c -> y (own row; all operands LDS-resident
    //      except the 2KB w1 row) ----
    {
      float w1r[8];
      const float4* zr = (const float4*)(zg + myrow * 512 + lane * 8);
      float4 za = zr[0], zb = zr[1];
      w1r[0] = za.x; w1r[1] = za.y; w1r[2] = za.z; w1r[3] = za.w;
      w1r[4] = zb.x; w1r[5] = zb.y; w1r[6] = zb.z; w1r[7] = zb.w;
      for (int tt = 0; tt < 12; ++tt) {
        const int t = wv * 12 + tt;
        half8 w2v = *(const half8*)(w2lds + t * 512 + lane * 8);
        float p = 0.f;
#pragma unroll
        for (int u = 0; u < 8; ++u)
          p += w3r[u] * fast_tanh(w1r[u] + (float)w2v[u]);
#pragma unroll
        for (int off = 32; off >= 1; off >>= 1) p += __shfl_xor(p, off);
        if (lane == 0) es[t] = p + b3v;
      }
      __syncthreads();
      if (wv == 0) {
        float e = (lane < 48) ? es[lane] : -1e30f;
        float mx = e;
#pragma unroll
        for (int off = 32; off >= 1; off >>= 1) mx = fmaxf(mx, __shfl_xor(mx, off));
        float pe = (lane < 48) ? fexp2((e - mx) * 1.4426950408889634f) : 0.f;
        float s = pe;
#pragma unroll
        for (int off = 32; off >= 1; off >>= 1) s += __shfl_xor(s, off);
        float a = pe * frcp(s);
        if (lane < 48) {
          asx[lane] = a;
          if (step == 47) out[128 + myrow * 48 + lane] = a;   // alpha (last step)
        }
      }
      __syncthreads();
      if (tid < 128) {
        float acc = 0.f;
#pragma unroll 4
        for (int t = 0; t < 48; ++t) acc += asx[t] * dxlds[t * 128 + tid];
        st_f32(yg + myrow * 132 + tid, acc);          // c -> y exchange
      } else if (tid < 131) {
        st_f32(yg + myrow * 132 + tid, xlds[step * 4 + (tid - 128)]);
      }
    }
    ++sync_no; flag_barrier(bar, myIdx, base16, sync_no, tid, lane, wv);
    acq_fence();

    // ---- ph3: col-sliced gi = y@Wc^T + bc ; GRU gates ; h_new.
    //      WcT slice in LDS(f32), gh in LDS, h in regs. ----
    {
      for (int i = tid; i < 528; i += 256) {
        const int r = i / 33, c = i - r * 33;
        *(float4*)(ylds + r * 132 + c * 4) =
            *(const float4*)(yg + (b0 + r) * 132 + c * 4);
      }
      __syncthreads();
      float aR0 = bcR0, aR1 = bcR1, aZ0 = bcZ0, aZ1 = bcZ1, aN0 = bcN0, aN1 = bcN1;
      const float* yrow = ylds + row3 * 132;
      const float* wk = wctlds + hp3 * 8;
#pragma unroll 4
      for (int k = 0; k < 131; ++k) {
        const float yk = yrow[k];
        const float4 wlo = *(const float4*)(wk + k * 128);
        const float4 whi = *(const float4*)(wk + k * 128 + 4);
        aR0 += yk * wlo.x; aZ0 += yk * wlo.y; aN0 += yk * wlo.z;
        aR1 += yk * whi.x; aZ1 += yk * whi.y; aN1 += yk * whi.z;
      }
      const float2 gR = *(const float2*)(ghlds + row3 * 32 + 2 * hp3);
      const float2 gZ = *(const float2*)(ghlds + 512 + row3 * 32 + 2 * hp3);
      const float2 gN = *(const float2*)(ghlds + 1024 + row3 * 32 + 2 * hp3);
      const float r0 = fast_sigmoid(aR0 + gR.x), r1 = fast_sigmoid(aR1 + gR.y);
      const float z0 = fast_sigmoid(aZ0 + gZ.x), z1 = fast_sigmoid(aZ1 + gZ.y);
      const float n0 = fast_tanh(aN0 + r0 * gN.x), n1 = fast_tanh(aN1 + r1 * gN.y);
      hA = (1.f - z0) * n0 + z0 * hA;
      hB = (1.f - z1) * n1 + z1 * hB;
      HU hh; hh.h[0] = (_Float16)hA; hh.h[1] = (_Float16)hB;
      st_u32((unsigned int*)(hgh + (b0 + row3) * 512 + gc), hh.u);  // h exchange
    }
    ++sync_no; flag_barrier(bar, myIdx, base16, sync_no, tid, lane, wv);
    acq_fence();
  }

  // ---- epilogue: re[row] = h_f . Wfc + bfc (partials across 16 blocks;
  //      out pre-initialized to bfc by prep; atomic order noise ~1e-6) ----
  {
    float p = hA * wfcA + hB * wfcB;
    p += __shfl_xor(p, 1); p += __shfl_xor(p, 2);
    p += __shfl_xor(p, 4); p += __shfl_xor(p, 8);
    if ((lane & 15) == 0) atomicAdd(out + b0 + row3, p);
  }
}

extern "C" void kernel_launch(void* const* d_in, const int* in_sizes, int n_in,
                              void* d_out, int out_size, void* d_ws, size_t ws_size,
                              hipStream_t stream) {
  (void)in_sizes; (void)n_in; (void)out_size; (void)ws_size;
  const float* dx  = (const float*)d_in[0];
  const float* xin = (const float*)d_in[1];
  const float* h0  = (const float*)d_in[2];
  const float* W1  = (const float*)d_in[3];
  const float* b1  = (const float*)d_in[4];
  const float* W2  = (const float*)d_in[5];
  const float* b2  = (const float*)d_in[6];
  const float* W3  = (const float*)d_in[7];
  const float* b3  = (const float*)d_in[8];
  const float* W4  = (const float*)d_in[9];
  const float* b4  = (const float*)d_in[10];
  const float* Wih = (const float*)d_in[11];
  const float* Whh = (const float*)d_in[12];
  const float* bih = (const float*)d_in[13];
  const float* bhh = (const float*)d_in[14];
  const float* Wfc = (const float*)d_in[15];
  const float* bfc = (const float*)d_in[16];

  char* ws = (char*)d_ws;
  unsigned int* bar = (unsigned int*)(ws + OFF_BAR);
  float*     bz  = (float*)(ws + OFF_BZ);
  float*     bc  = (float*)(ws + OFF_BC);
  _Float16*  Wzh = (_Float16*)(ws + OFF_WZ);
  _Float16*  WcT = (_Float16*)(ws + OFF_WCT);
  _Float16*  w2h = (_Float16*)(ws + OFF_W2H);
  _Float16*  hgh = (_Float16*)(ws + OFF_HGH);
  float*     zg  = (float*)(ws + OFF_ZG);
  float*     yg  = (float*)(ws + OFF_Y);

  prep_all<<<322, 256, 0, stream>>>(dx, h0, W1, Whh, b1, bhh, Wih, W4, b4, bih,
                                    W2, b2, bfc, hgh, Wzh, bz, bc, WcT, w2h,
                                    bar, (float*)d_out);
  decoder_main<<<128, 256, 0, stream>>>(dx, xin, h0, W3, b3, Wfc,
                                        Wzh, bz, WcT, bc, w2h,
                                        hgh, zg, yg, bar, (float*)d_out);
}

// Round 2
// 1154.029 us; speedup vs baseline: 1.5119x; 1.5119x over previous
//
#include <hip/hip_runtime.h>

// B=128, T=48, I=128, H=512. Sequential 48-step attention+GRU scan.
// R7: 2-barrier (R5) structure + DW precompute.
//  - ph1: z = h @ [W1|W_hh]^T col-sliced MFMA, weights persistent in regs.
//    h staged cooperatively (2048x8B bypass loads) into swizzled LDS, then
//    ds_read_b128 A-frags (bank-balanced).
//  - ph2: row-owned attention (w2h in LDS), softmax -> a.
//  - ph3 (fused, row-local): gi = sum_t a_t * DW[row,t,:] + x-part(regs) + bc,
//    GRU gates with gh from z (bypass), h update in regs.
//    DW[b,t,o] = dx[b,t,:] @ Wc[o,:128]^T precomputed (f16, 18.9MB, L2-resident
//    per XCD: 16 rows x 147KB = 2.36MB < 4MB). NO fences -> L2 stays warm.
//  - Exchanges: write-through agent stores + relaxed flag barrier (R5-proven);
//    bypass agent loads for h/z only. 2 barriers/step.

typedef _Float16 half8 __attribute__((ext_vector_type(8)));
typedef _Float16 h2v  __attribute__((ext_vector_type(2)));
typedef float    f32x4 __attribute__((ext_vector_type(4)));

// ---------------- ws layout (bytes) ----------------
#define OFF_BAR   0u          // 128 flags * 128B (zeroed by prep)
#define OFF_BZ    32768u      // 2048 f32 : [b1 ; b_hh]
#define OFF_BC    40960u      // 1536 f32 : W_ih@b4 + b_ih
#define OFF_WZ    65536u      // 2048*512 f16 : [W1 ; W_hh] row-major
#define OFF_WCT   2162688u    // 131*1536 f16 : (W_ih@W4)^T, k-major
#define OFF_W2H   3178496u    // 128*48*512 f16 : dx@W2^T + b2
#define OFF_HGH   9732096u    // 128*512 f16 : h (cross-block exchange)
#define OFF_ZG    9863168u    // 128*2048 f32 : z = [w1 | gh]
#define OFF_DW    10911744u   // 6144*1536 f16 : dx@Wc^T  (18.87 MB)
// total ws use: 29,786,112 B

__device__ __forceinline__ float fexp2(float x) { return __builtin_amdgcn_exp2f(x); }
__device__ __forceinline__ float frcp(float x)  { return __builtin_amdgcn_rcpf(x); }
__device__ __forceinline__ float fast_tanh(float x) {
  x = fminf(fmaxf(x, -15.f), 15.f);
  float e = fexp2(x * 2.8853900817779268f);   // exp(2x)
  return (e - 1.f) * frcp(e + 1.f);
}
__device__ __forceinline__ float fast_sigmoid(float x) {
  x = fminf(fmaxf(x, -30.f), 30.f);
  float e = fexp2(x * 1.4426950408889634f);   // exp(x)
  return e * frcp(e + 1.f);
}

// ---- coherent (agent-scope, per-access) data movement ----
__device__ __forceinline__ void st_f32(float* p, float v) {
  __hip_atomic_store(p, v, __ATOMIC_RELAXED, __HIP_MEMORY_SCOPE_AGENT);
}
__device__ __forceinline__ unsigned long long ld_u64(const void* p) {
  return __hip_atomic_load((const unsigned long long*)p, __ATOMIC_RELAXED,
                           __HIP_MEMORY_SCOPE_AGENT);
}
__device__ __forceinline__ void st_u32(unsigned int* p, unsigned int v) {
  __hip_atomic_store(p, v, __ATOMIC_RELAXED, __HIP_MEMORY_SCOPE_AGENT);
}
union U2 { unsigned long long u; float f[2]; };
union H4 { unsigned long long u; _Float16 h[4]; };
union HU { unsigned int u; h2v h; };

// All-relaxed flag barrier (R5-proven). __syncthreads() emits s_waitcnt
// vmcnt(0) so all prior write-through stores are ACKED at the MALL before the
// flag store issues; pollers use agent-scope loads -> always see MALL.
__device__ __forceinline__ void flag_barrier(unsigned int* flags, int myIdx,
                                             int base16, unsigned int target,
                                             int tid, int lane, int wv) {
  __syncthreads();   // drains vmcnt: all sc stores acked at coherence point
  if (tid == 0)
    __hip_atomic_store(flags + myIdx * 32, target, __ATOMIC_RELAXED,
                       __HIP_MEMORY_SCOPE_AGENT);
  if (wv == 0) {
    unsigned int* fp = flags + (base16 + (lane & 15)) * 32;
    for (;;) {
      unsigned int v = (lane < 16)
        ? __hip_atomic_load(fp, __ATOMIC_RELAXED, __HIP_MEMORY_SCOPE_AGENT)
        : target;
      if ((__ballot(v < target) & 0xFFFFull) == 0) break;
      __builtin_amdgcn_s_sleep(1);
    }
    __asm__ __volatile__("" ::: "memory");
  }
  __syncthreads();
}

// ---------------- fused prep kernel (grid 322 x 256) ----------------
__global__ __launch_bounds__(256) void prep_all(
    const float* __restrict__ dx, const float* __restrict__ h0,
    const float* __restrict__ W1, const float* __restrict__ Whh,
    const float* __restrict__ b1, const float* __restrict__ bhh,
    const float* __restrict__ Wih, const float* __restrict__ W4,
    const float* __restrict__ b4, const float* __restrict__ bih,
    const float* __restrict__ W2, const float* __restrict__ b2,
    _Float16* __restrict__ hgh,
    _Float16* __restrict__ Wzh, float* __restrict__ bz,
    float* __restrict__ bc, _Float16* __restrict__ WcT,
    _Float16* __restrict__ w2h, unsigned int* __restrict__ bar)
{
  __shared__ __align__(16) char smem[58368];
  const int bid = blockIdx.x;
  const int tid = threadIdx.x;
  const int lane = tid & 63, wv = tid >> 6;

  if (bid == 0) {                       // zero flag region (8192 u32)
    for (int i = tid; i < 8192; i += 256) bar[i] = 0u;
  } else if (bid == 1) {                // bz
    for (int n = tid; n < 2048; n += 256)
      bz[n] = (n < 512) ? b1[n] : bhh[n - 512];
  } else if (bid < 18) {                // bc: 16 blocks x 96 rows, wave/row
    const int o0 = (bid - 2) * 96 + wv * 24;
    for (int it = 0; it < 24; ++it) {
      const int row = o0 + it;
      const float* r = Wih + row * 512 + lane * 8;
      float s = 0.f;
#pragma unroll
      for (int u = 0; u < 8; ++u) s += r[u] * b4[lane * 8 + u];
#pragma unroll
      for (int off = 32; off >= 1; off >>= 1) s += __shfl_xor(s, off);
      if (lane == 0) bc[row] = bih[row] + s;
    }
  } else if (bid < 34) {                // hgh init (f16 copy of h0)
    const int i0 = (bid - 18) * 4096 + tid * 16;
#pragma unroll
    for (int u = 0; u < 4; ++u) {
      float4 v = *(const float4*)(h0 + i0 + u * 4);
      H4 p; p.h[0] = (_Float16)v.x; p.h[1] = (_Float16)v.y;
      p.h[2] = (_Float16)v.z; p.h[3] = (_Float16)v.w;
      *(unsigned long long*)(hgh + i0 + u * 4) = p.u;
    }
  } else if (bid < 98) {                // Wzh = f16([W1;Whh]) flat copy
    const int i0 = (bid - 34) * 16384 + tid * 64;
#pragma unroll 4
    for (int u = 0; u < 16; ++u) {
      const int i = i0 + u * 4;
      const float* src = (i < 262144) ? (W1 + i) : (Whh + i - 262144);
      float4 v = *(const float4*)src;
      H4 p; p.h[0] = (_Float16)v.x; p.h[1] = (_Float16)v.y;
      p.h[2] = (_Float16)v.z; p.h[3] = (_Float16)v.w;
      *(unsigned long long*)(Wzh + i) = p.u;
    }
  } else if (bid < 194) {               // WcT[k][o] = (Wih@W4)[o][k]
    float* wih = (float*)smem;                 // 16*66
    float* w4s = (float*)(smem + 4224);        // 64*132
    const int o0 = (bid - 98) * 16;
    const int k = tid;
    float acc[16];
#pragma unroll
    for (int i = 0; i < 16; ++i) acc[i] = 0.f;
    for (int jc = 0; jc < 512; jc += 64) {
      __syncthreads();
      for (int idx = tid; idx < 16 * 64; idx += 256) {
        int oo = idx >> 6, jj = idx & 63;
        wih[oo * 66 + jj] = Wih[(o0 + oo) * 512 + jc + jj];
      }
      for (int idx = tid; idx < 64 * 131; idx += 256) {
        int r = idx / 131, c = idx - r * 131;
        w4s[r * 132 + c] = W4[(jc + r) * 131 + c];
      }
      __syncthreads();
      if (k < 131) {
        for (int jj = 0; jj < 64; ++jj) {
          float w4v = w4s[jj * 132 + k];
#pragma unroll
          for (int oo = 0; oo < 16; ++oo) acc[oo] += wih[oo * 66 + jj] * w4v;
        }
      }
    }
    if (k < 131) {
#pragma unroll
      for (int oo = 0; oo < 16; ++oo)
        WcT[k * 1536 + o0 + oo] = (_Float16)acc[oo];
    }
  } else {                              // w2h: 128 blocks, one batch row each
    float* dxa = (float*)smem;                 // 48*128 f32
    _Float16* w2t = (_Float16*)(smem + 24576); // 128*132 f16
    const int b = bid - 194;
    for (int idx = tid; idx < 48 * 128; idx += 256)
      dxa[idx] = dx[b * 6144 + idx];
    for (int hc = 0; hc < 4; ++hc) {
      __syncthreads();
      for (int idx = tid; idx < 128 * 128; idx += 256) {
        int hl = idx >> 7, i = idx & 127;
        w2t[i * 132 + hl] = (_Float16)W2[(hc * 128 + hl) * 128 + i];
      }
      __syncthreads();
      const int hh = tid & 127;
      const int tq = tid >> 7;
      const float b2v = b2[hc * 128 + hh];
      for (int tt = tq * 24; tt < tq * 24 + 24; ++tt) {
        float acc = b2v;
#pragma unroll 4
        for (int i = 0; i < 128; ++i)
          acc += dxa[tt * 128 + i] * (float)w2t[i * 132 + hh];
        w2h[(b * 48 + tt) * 512 + hc * 128 + hh] = (_Float16)acc;
      }
    }
  }
}

// ---------------- DW precompute (grid 384 x 256, after prep_all) -----------
// DW[unit][o] = sum_{i<128} dx[unit][i] * Wc[o][i],  unit = b*48+t, o<1536.
__global__ __launch_bounds__(256) void prep_dw(
    const float* __restrict__ dx, const _Float16* __restrict__ WcT,
    _Float16* __restrict__ DW)
{
  __shared__ float dxu[16 * 128];
  const int j = blockIdx.x;          // 0..383
  const int tid = threadIdx.x;
  const int u0 = j * 16;             // 16 consecutive units
  const float4* src = (const float4*)(dx + (size_t)u0 * 128);
  float4* dst4 = (float4*)dxu;
  for (int i = tid; i < 512; i += 256) dst4[i] = src[i];
  __syncthreads();
  const int c0 = tid * 2;
  float acc[16][6];
#pragma unroll
  for (int u = 0; u < 16; ++u)
#pragma unroll
    for (int g = 0; g < 6; ++g) acc[u][g] = 0.f;
  for (int k = 0; k < 128; ++k) {
    const _Float16* wr = WcT + k * 1536 + c0;
    h2v w0 = *(const h2v*)(wr);
    h2v w1v = *(const h2v*)(wr + 512);
    h2v w2v = *(const h2v*)(wr + 1024);
    const float f0 = (float)w0[0],  f1 = (float)w0[1];
    const float f2 = (float)w1v[0], f3 = (float)w1v[1];
    const float f4 = (float)w2v[0], f5 = (float)w2v[1];
#pragma unroll
    for (int u = 0; u < 16; ++u) {
      const float d = dxu[u * 128 + k];
      acc[u][0] += d * f0; acc[u][1] += d * f1; acc[u][2] += d * f2;
      acc[u][3] += d * f3; acc[u][4] += d * f4; acc[u][5] += d * f5;
    }
  }
#pragma unroll
  for (int u = 0; u < 16; ++u) {
    _Float16* o = DW + (size_t)(u0 + u) * 1536 + c0;
    HU p;
    p.h[0] = (_Float16)acc[u][0]; p.h[1] = (_Float16)acc[u][1];
    *(unsigned int*)(o) = p.u;
    p.h[0] = (_Float16)acc[u][2]; p.h[1] = (_Float16)acc[u][3];
    *(unsigned int*)(o + 512) = p.u;
    p.h[0] = (_Float16)acc[u][4]; p.h[1] = (_Float16)acc[u][5];
    *(unsigned int*)(o + 1024) = p.u;
  }
}

// ---------------- main persistent scan kernel ----------------
__global__ __launch_bounds__(256, 1) void decoder_main(
    const float* __restrict__ xin, const float* __restrict__ h0,
    const float* __restrict__ W3, const float* __restrict__ b3,
    const float* __restrict__ Wfc, const float* __restrict__ bfc,
    const _Float16* __restrict__ Wzh, const float* __restrict__ bz,
    const _Float16* __restrict__ WcT, const float* __restrict__ bc,
    const _Float16* __restrict__ w2h, const _Float16* __restrict__ DW,
    _Float16* __restrict__ hgh, float* __restrict__ zg,
    unsigned int* __restrict__ bar, float* __restrict__ out)
{
  const int tid  = threadIdx.x;
  const int lane = tid & 63;
  const int wv   = tid >> 6;
  const int bid  = blockIdx.x;
  const int grp  = bid & 7;      // XCD-local heuristic (perf only)
  const int mem  = bid >> 3;     // 0..15
  const int b0   = grp * 16;
  const int myrow = b0 + mem;    // this block's row (ph2+ph3)
  const int cb   = mem * 128;    // ph1 column base (of 2048)
  const int myIdx = grp * 16 + mem;
  const int base16 = grp * 16;
  unsigned int sync_no = 0;

  __shared__ __align__(16) _Float16 w2lds[48 * 512];  // 48 KiB
  __shared__ __align__(16) char hlds[16384];          // 16 KiB, swizzled h
  __shared__ float xlds[48 * 4];
  __shared__ float wfcs[512];
  __shared__ float es[48];
  __shared__ float asx[48];
  __shared__ float red[4];

  const int m = lane & 15, q = lane >> 4;

  // ---- ph1 persistent weights: 2 col-tiles of 16 per wave (R5 layout) ----
  half8 wzf[2][16];
  int   ncol[2];
  float bzv[2];
#pragma unroll
  for (int t = 0; t < 2; ++t) {
    ncol[t] = cb + (wv * 2 + t) * 16 + m;
    const _Float16* wrow = Wzh + ncol[t] * 512 + q * 8;
#pragma unroll
    for (int ks = 0; ks < 16; ++ks)
      wzf[t][ks] = *(const half8*)(wrow + ks * 32);
    bzv[t] = bz[ncol[t]];
  }
  float w3r[8];
#pragma unroll
  for (int u = 0; u < 8; ++u) w3r[u] = W3[lane * 8 + u];
  const float b3v  = b3[0];
  const float bfcv = bfc[0];

  // ---- ph3 per-thread state: owns h-cols (c0, c0+1) of row myrow ----
  const int c0 = tid * 2;
  const float bcR0 = bc[c0],        bcR1 = bc[c0 + 1];
  const float bcZ0 = bc[512 + c0],  bcZ1 = bc[513 + c0];
  const float bcN0 = bc[1024 + c0], bcN1 = bc[1025 + c0];
  // x-part weights (Wc cols 128..130), persistent f32
  float wxR[3][2], wxZ[3][2], wxN[3][2];
#pragma unroll
  for (int j2 = 0; j2 < 3; ++j2) {
    const _Float16* wr = WcT + (128 + j2) * 1536 + c0;
    wxR[j2][0] = (float)wr[0];    wxR[j2][1] = (float)wr[1];
    wxZ[j2][0] = (float)wr[512];  wxZ[j2][1] = (float)wr[513];
    wxN[j2][0] = (float)wr[1024]; wxN[j2][1] = (float)wr[1025];
  }
  float hA = h0[myrow * 512 + c0];
  float hB = h0[myrow * 512 + c0 + 1];

  // ---- one-time LDS preload ----
  {
    const half8* w2src = (const half8*)(w2h + (size_t)myrow * 48 * 512);
    half8* w2dst = (half8*)w2lds;
    for (int i = tid; i < 3072; i += 256) w2dst[i] = w2src[i];
    for (int i = tid; i < 512; i += 256) wfcs[i] = Wfc[i];
    for (int i = tid; i < 144; i += 256) {
      const int t = i / 3, j2 = i - t * 3;
      xlds[t * 4 + j2] = xin[myrow * 144 + i];
    }
  }
  __syncthreads();

  const float* __restrict__ zrow = zg + (size_t)myrow * 2048;
  const _Float16* __restrict__ dwbase = DW + (size_t)myrow * 48 * 1536 + c0;

  for (int step = 0; step < 48; ++step) {
    // ---- stage h (cross-block, bypass) -> swizzled hlds ----
    {
#pragma unroll
      for (int u = 0; u < 8; ++u) {
        const int n = u * 256 + tid;                    // 8B chunk id, n<2048
        unsigned long long v =
            ld_u64((const char*)hgh + (size_t)b0 * 1024 + (size_t)n * 8);
        const int row = n >> 7, b8 = (n & 127) * 8;
        *(unsigned long long*)(hlds + row * 1024 + (b8 ^ ((row & 7) << 4))) = v;
      }
    }
    __syncthreads();

    // ---- ph1: z[16,2048] = h @ [W1|W_hh]^T + bz (MFMA, weights in regs) ----
    {
      half8 af[16];
      const char* hb = hlds + m * 1024;
      const int sw = (m & 7) << 4;
#pragma unroll
      for (int ks = 0; ks < 16; ++ks)
        af[ks] = *(const half8*)(hb + ((ks * 64 + q * 16) ^ sw));
#pragma unroll
      for (int t = 0; t < 2; ++t) {
        f32x4 acc = {bzv[t], bzv[t], bzv[t], bzv[t]};
#pragma unroll
        for (int ks = 0; ks < 16; ++ks)
          acc = __builtin_amdgcn_mfma_f32_16x16x32_f16(af[ks], wzf[t][ks], acc, 0, 0, 0);
#pragma unroll
        for (int r = 0; r < 4; ++r)
          st_f32(&zg[(size_t)(b0 + q * 4 + r) * 2048 + ncol[t]], acc[r]);
      }
    }
    ++sync_no; flag_barrier(bar, myIdx, base16, sync_no, tid, lane, wv);

    // ---- ph2: e -> softmax (own row, block-local) ----
    {
      float w1r[8];
#pragma unroll
      for (int u2 = 0; u2 < 4; ++u2) {
        U2 t2; t2.u = ld_u64(zrow + lane * 8 + u2 * 2);
        w1r[u2 * 2] = t2.f[0]; w1r[u2 * 2 + 1] = t2.f[1];
      }
      for (int tt = 0; tt < 12; ++tt) {
        const int t = wv * 12 + tt;
        half8 w2v = *(const half8*)(w2lds + t * 512 + lane * 8);
        float p = 0.f;
#pragma unroll
        for (int u = 0; u < 8; ++u)
          p += w3r[u] * fast_tanh(w1r[u] + (float)w2v[u]);
#pragma unroll
        for (int off = 32; off >= 1; off >>= 1) p += __shfl_xor(p, off);
        if (lane == 0) es[t] = p + b3v;
      }
      __syncthreads();
      if (wv == 0) {
        float e = (lane < 48) ? es[lane] : -1e30f;
        float mx = e;
#pragma unroll
        for (int off = 32; off >= 1; off >>= 1) mx = fmaxf(mx, __shfl_xor(mx, off));
        float pe = (lane < 48) ? fexp2((e - mx) * 1.4426950408889634f) : 0.f;
        float s = pe;
#pragma unroll
        for (int off = 32; off >= 1; off >>= 1) s += __shfl_xor(s, off);
        float a = pe * frcp(s);
        if (lane < 48) {
          asx[lane] = a;
          if (step == 47) out[128 + myrow * 48 + lane] = a;   // alpha (last step)
        }
      }
      __syncthreads();
    }

    // ---- ph3: gi = sum_t a_t*DW + x-part + bc ; GRU ; h_new (row-local) ----
    {
      float aR0 = bcR0, aR1 = bcR1, aZ0 = bcZ0, aZ1 = bcZ1, aN0 = bcN0, aN1 = bcN1;
#pragma unroll 4
      for (int t = 0; t < 48; ++t) {
        const float a = asx[t];
        const _Float16* p = dwbase + t * 1536;
        h2v d0 = *(const h2v*)(p);
        h2v d1 = *(const h2v*)(p + 512);
        h2v d2 = *(const h2v*)(p + 1024);
        aR0 += a * (float)d0[0]; aR1 += a * (float)d0[1];
        aZ0 += a * (float)d1[0]; aZ1 += a * (float)d1[1];
        aN0 += a * (float)d2[0]; aN1 += a * (float)d2[1];
      }
      const float x0 = xlds[step * 4], x1 = xlds[step * 4 + 1], x2 = xlds[step * 4 + 2];
      aR0 += x0 * wxR[0][0] + x1 * wxR[1][0] + x2 * wxR[2][0];
      aR1 += x0 * wxR[0][1] + x1 * wxR[1][1] + x2 * wxR[2][1];
      aZ0 += x0 * wxZ[0][0] + x1 * wxZ[1][0] + x2 * wxZ[2][0];
      aZ1 += x0 * wxZ[0][1] + x1 * wxZ[1][1] + x2 * wxZ[2][1];
      aN0 += x0 * wxN[0][0] + x1 * wxN[1][0] + x2 * wxN[2][0];
      aN1 += x0 * wxN[0][1] + x1 * wxN[1][1] + x2 * wxN[2][1];
      U2 tr, tz, tn2;
      tr.u  = ld_u64(zrow + 512 + c0);
      tz.u  = ld_u64(zrow + 1024 + c0);
      tn2.u = ld_u64(zrow + 1536 + c0);
      const float r0 = fast_sigmoid(aR0 + tr.f[0]), r1 = fast_sigmoid(aR1 + tr.f[1]);
      const float z0 = fast_sigmoid(aZ0 + tz.f[0]), z1 = fast_sigmoid(aZ1 + tz.f[1]);
      const float n0 = fast_tanh(aN0 + r0 * tn2.f[0]), n1 = fast_tanh(aN1 + r1 * tn2.f[1]);
      hA = (1.f - z0) * n0 + z0 * hA;
      hB = (1.f - z1) * n1 + z1 * hB;
      HU hp; hp.h[0] = (_Float16)hA; hp.h[1] = (_Float16)hB;
      st_u32((unsigned int*)(hgh + myrow * 512 + c0), hp.u);   // h exchange
    }
    ++sync_no; flag_barrier(bar, myIdx, base16, sync_no, tid, lane, wv);
  }

  // ---- epilogue: re[myrow] = h_f . Wfc + bfc (h in registers) ----
  {
    float p = hA * wfcs[c0] + hB * wfcs[c0 + 1];
#pragma unroll
    for (int off = 32; off >= 1; off >>= 1) p += __shfl_xor(p, off);
    if (lane == 0) red[wv] = p;
    __syncthreads();
    if (tid == 0) out[myrow] = red[0] + red[1] + red[2] + red[3] + bfcv;
  }
}

extern "C" void kernel_launch(void* const* d_in, const int* in_sizes, int n_in,
                              void* d_out, int out_size, void* d_ws, size_t ws_size,
                              hipStream_t stream) {
  (void)in_sizes; (void)n_in; (void)out_size; (void)ws_size;
  const float* dx  = (const float*)d_in[0];
  const float* xin = (const float*)d_in[1];
  const float* h0  = (const float*)d_in[2];
  const float* W1  = (const float*)d_in[3];
  const float* b1  = (const float*)d_in[4];
  const float* W2  = (const float*)d_in[5];
  const float* b2  = (const float*)d_in[6];
  const float* W3  = (const float*)d_in[7];
  const float* b3  = (const float*)d_in[8];
  const float* W4  = (const float*)d_in[9];
  const float* b4  = (const float*)d_in[10];
  const float* Wih = (const float*)d_in[11];
  const float* Whh = (const float*)d_in[12];
  const float* bih = (const float*)d_in[13];
  const float* bhh = (const float*)d_in[14];
  const float* Wfc = (const float*)d_in[15];
  const float* bfc = (const float*)d_in[16];

  char* ws = (char*)d_ws;
  unsigned int* bar = (unsigned int*)(ws + OFF_BAR);
  float*     bz  = (float*)(ws + OFF_BZ);
  float*     bc  = (float*)(ws + OFF_BC);
  _Float16*  Wzh = (_Float16*)(ws + OFF_WZ);
  _Float16*  WcT = (_Float16*)(ws + OFF_WCT);
  _Float16*  w2h = (_Float16*)(ws + OFF_W2H);
  _Float16*  hgh = (_Float16*)(ws + OFF_HGH);
  float*     zg  = (float*)(ws + OFF_ZG);
  _Float16*  DW  = (_Float16*)(ws + OFF_DW);

  prep_all<<<322, 256, 0, stream>>>(dx, h0, W1, Whh, b1, bhh, Wih, W4, b4, bih,
                                    W2, b2, hgh, Wzh, bz, bc, WcT, w2h, bar);
  prep_dw<<<384, 256, 0, stream>>>(dx, WcT, DW);
  decoder_main<<<128, 256, 0, stream>>>(xin, h0, W3, b3, Wfc, bfc,
                                        Wzh, bz, WcT, bc, w2h, DW,
                                        hgh, zg, bar, (float*)d_out);
}

// Round 3
// 876.942 us; speedup vs baseline: 1.9896x; 1.3160x over previous
//
#include <hip/hip_runtime.h>

// B=128, T=48, I=128, H=512. Sequential 48-step attention+GRU scan.
// R8: barrier-free producer/consumer dataflow (flags only).
//  - zflag[block] raised after ph1 z-store drain; hflag[row] raised after ph3.
//  - ph2 polls only blocks 0..3 (w1 cols); ph3 polls 4..15 (gh cols); h-stage
//    polls per-row flags per-wave. No global 16-block resync anywhere.
//  - Single-buffered zg/hgh stay race-free: every overwrite is transitively
//    gated on all peers' flags, which are raised only after their reads of
//    the previous value completed (vmcnt drained at __syncthreads before
//    each flag store).
//  - DW repacked 12B-contiguous per (t,thread): dwordx3 loads + 3-bank
//    register pipeline; gh bypass loads issued before the DW loop (hidden).
//  - All exchange traffic: relaxed agent-scope (MALL-coherent) ops, R5-proven.

typedef _Float16 half8 __attribute__((ext_vector_type(8)));
typedef _Float16 h2v  __attribute__((ext_vector_type(2)));
typedef float    f32x4 __attribute__((ext_vector_type(4)));
typedef unsigned int u32x3 __attribute__((ext_vector_type(3)));

// ---------------- ws layout (bytes) ----------------
#define OFF_BAR   0u          // flags: zflag[128]*128B @0, hflag[128]*128B @16K
#define OFF_BZ    32768u      // 2048 f32 : [b1 ; b_hh]
#define OFF_BC    40960u      // 1536 f32 : W_ih@b4 + b_ih
#define OFF_WZ    65536u      // 2048*512 f16 : [W1 ; W_hh] row-major
#define OFF_WCT   2162688u    // 131*1536 f16 : (W_ih@W4)^T, k-major
#define OFF_W2H   3178496u    // 128*48*512 f16 : dx@W2^T + b2
#define OFF_HGH   9732096u    // 128*512 f16 : h (cross-block exchange)
#define OFF_ZG    9863168u    // 128*2048 f32 : z = [w1 | gh]
#define OFF_DW    10911744u   // 6144*256*3 u32 : dx@Wc^T packed 12B/(t,pair)
// total ws use: 29,786,112 B

__device__ __forceinline__ float fexp2(float x) { return __builtin_amdgcn_exp2f(x); }
__device__ __forceinline__ float frcp(float x)  { return __builtin_amdgcn_rcpf(x); }
__device__ __forceinline__ float fast_tanh(float x) {
  x = fminf(fmaxf(x, -15.f), 15.f);
  float e = fexp2(x * 2.8853900817779268f);   // exp(2x)
  return (e - 1.f) * frcp(e + 1.f);
}
__device__ __forceinline__ float fast_sigmoid(float x) {
  x = fminf(fmaxf(x, -30.f), 30.f);
  float e = fexp2(x * 1.4426950408889634f);   // exp(x)
  return e * frcp(e + 1.f);
}

// ---- coherent (agent-scope, per-access) data movement ----
__device__ __forceinline__ void st_f32(float* p, float v) {
  __hip_atomic_store(p, v, __ATOMIC_RELAXED, __HIP_MEMORY_SCOPE_AGENT);
}
__device__ __forceinline__ unsigned long long ld_u64(const void* p) {
  return __hip_atomic_load((const unsigned long long*)p, __ATOMIC_RELAXED,
                           __HIP_MEMORY_SCOPE_AGENT);
}
__device__ __forceinline__ void st_u32(unsigned int* p, unsigned int v) {
  __hip_atomic_store(p, v, __ATOMIC_RELAXED, __HIP_MEMORY_SCOPE_AGENT);
}
union U2 { unsigned long long u; float f[2]; };
union H4 { unsigned long long u; _Float16 h[4]; };
union HU { unsigned int u; h2v h; };

// Wait until *fp >= target on all active lanes (inactive lanes auto-pass).
__device__ __forceinline__ void poll_ge(unsigned int* fp, bool active,
                                        unsigned int target) {
  for (;;) {
    unsigned int v = active
      ? __hip_atomic_load(fp, __ATOMIC_RELAXED, __HIP_MEMORY_SCOPE_AGENT)
      : target;
    if (__ballot(v < target) == 0) break;
    __builtin_amdgcn_s_sleep(1);
  }
  __asm__ __volatile__("" ::: "memory");
}

// ---------------- fused prep kernel (grid 322 x 256) ----------------
__global__ __launch_bounds__(256) void prep_all(
    const float* __restrict__ dx, const float* __restrict__ h0,
    const float* __restrict__ W1, const float* __restrict__ Whh,
    const float* __restrict__ b1, const float* __restrict__ bhh,
    const float* __restrict__ Wih, const float* __restrict__ W4,
    const float* __restrict__ b4, const float* __restrict__ bih,
    const float* __restrict__ W2, const float* __restrict__ b2,
    _Float16* __restrict__ hgh,
    _Float16* __restrict__ Wzh, float* __restrict__ bz,
    float* __restrict__ bc, _Float16* __restrict__ WcT,
    _Float16* __restrict__ w2h, unsigned int* __restrict__ bar)
{
  __shared__ __align__(16) char smem[58368];
  const int bid = blockIdx.x;
  const int tid = threadIdx.x;
  const int lane = tid & 63, wv = tid >> 6;

  if (bid == 0) {                       // zero flag region (8192 u32)
    for (int i = tid; i < 8192; i += 256) bar[i] = 0u;
  } else if (bid == 1) {                // bz
    for (int n = tid; n < 2048; n += 256)
      bz[n] = (n < 512) ? b1[n] : bhh[n - 512];
  } else if (bid < 18) {                // bc: 16 blocks x 96 rows, wave/row
    const int o0 = (bid - 2) * 96 + wv * 24;
    for (int it = 0; it < 24; ++it) {
      const int row = o0 + it;
      const float* r = Wih + row * 512 + lane * 8;
      float s = 0.f;
#pragma unroll
      for (int u = 0; u < 8; ++u) s += r[u] * b4[lane * 8 + u];
#pragma unroll
      for (int off = 32; off >= 1; off >>= 1) s += __shfl_xor(s, off);
      if (lane == 0) bc[row] = bih[row] + s;
    }
  } else if (bid < 34) {                // hgh init (f16 copy of h0)
    const int i0 = (bid - 18) * 4096 + tid * 16;
#pragma unroll
    for (int u = 0; u < 4; ++u) {
      float4 v = *(const float4*)(h0 + i0 + u * 4);
      H4 p; p.h[0] = (_Float16)v.x; p.h[1] = (_Float16)v.y;
      p.h[2] = (_Float16)v.z; p.h[3] = (_Float16)v.w;
      *(unsigned long long*)(hgh + i0 + u * 4) = p.u;
    }
  } else if (bid < 98) {                // Wzh = f16([W1;Whh]) flat copy
    const int i0 = (bid - 34) * 16384 + tid * 64;
#pragma unroll 4
    for (int u = 0; u < 16; ++u) {
      const int i = i0 + u * 4;
      const float* src = (i < 262144) ? (W1 + i) : (Whh + i - 262144);
      float4 v = *(const float4*)src;
      H4 p; p.h[0] = (_Float16)v.x; p.h[1] = (_Float16)v.y;
      p.h[2] = (_Float16)v.z; p.h[3] = (_Float16)v.w;
      *(unsigned long long*)(Wzh + i) = p.u;
    }
  } else if (bid < 194) {               // WcT[k][o] = (Wih@W4)[o][k]
    float* wih = (float*)smem;                 // 16*66
    float* w4s = (float*)(smem + 4224);        // 64*132
    const int o0 = (bid - 98) * 16;
    const int k = tid;
    float acc[16];
#pragma unroll
    for (int i = 0; i < 16; ++i) acc[i] = 0.f;
    for (int jc = 0; jc < 512; jc += 64) {
      __syncthreads();
      for (int idx = tid; idx < 16 * 64; idx += 256) {
        int oo = idx >> 6, jj = idx & 63;
        wih[oo * 66 + jj] = Wih[(o0 + oo) * 512 + jc + jj];
      }
      for (int idx = tid; idx < 64 * 131; idx += 256) {
        int r = idx / 131, c = idx - r * 131;
        w4s[r * 132 + c] = W4[(jc + r) * 131 + c];
      }
      __syncthreads();
      if (k < 131) {
        for (int jj = 0; jj < 64; ++jj) {
          float w4v = w4s[jj * 132 + k];
#pragma unroll
          for (int oo = 0; oo < 16; ++oo) acc[oo] += wih[oo * 66 + jj] * w4v;
        }
      }
    }
    if (k < 131) {
#pragma unroll
      for (int oo = 0; oo < 16; ++oo)
        WcT[k * 1536 + o0 + oo] = (_Float16)acc[oo];
    }
  } else {                              // w2h: 128 blocks, one batch row each
    float* dxa = (float*)smem;                 // 48*128 f32
    _Float16* w2t = (_Float16*)(smem + 24576); // 128*132 f16
    const int b = bid - 194;
    for (int idx = tid; idx < 48 * 128; idx += 256)
      dxa[idx] = dx[b * 6144 + idx];
    for (int hc = 0; hc < 4; ++hc) {
      __syncthreads();
      for (int idx = tid; idx < 128 * 128; idx += 256) {
        int hl = idx >> 7, i = idx & 127;
        w2t[i * 132 + hl] = (_Float16)W2[(hc * 128 + hl) * 128 + i];
      }
      __syncthreads();
      const int hh = tid & 127;
      const int tq = tid >> 7;
      const float b2v = b2[hc * 128 + hh];
      for (int tt = tq * 24; tt < tq * 24 + 24; ++tt) {
        float acc = b2v;
#pragma unroll 4
        for (int i = 0; i < 128; ++i)
          acc += dxa[tt * 128 + i] * (float)w2t[i * 132 + hh];
        w2h[(b * 48 + tt) * 512 + hc * 128 + hh] = (_Float16)acc;
      }
    }
  }
}

// ---------------- DW precompute (grid 384 x 256, after prep_all) -----------
// Packed layout: DW12[unit][pair][3 u32], pair = h-col pair, 12B contiguous:
// {(R0,R1),(Z0,Z1),(N0,N1)} f16 pairs for cols (2*pair, 2*pair+1).
__global__ __launch_bounds__(256) void prep_dw(
    const float* __restrict__ dx, const _Float16* __restrict__ WcT,
    unsigned int* __restrict__ DW12)
{
  __shared__ float dxu[16 * 128];
  const int j = blockIdx.x;          // 0..383
  const int tid = threadIdx.x;
  const int u0 = j * 16;             // 16 consecutive units
  const float4* src = (const float4*)(dx + (size_t)u0 * 128);
  float4* dst4 = (float4*)dxu;
  for (int i = tid; i < 512; i += 256) dst4[i] = src[i];
  __syncthreads();
  const int c0 = tid * 2;
  float acc[16][6];
#pragma unroll
  for (int u = 0; u < 16; ++u)
#pragma unroll
    for (int g = 0; g < 6; ++g) acc[u][g] = 0.f;
  for (int k = 0; k < 128; ++k) {
    const _Float16* wr = WcT + k * 1536 + c0;
    h2v w0 = *(const h2v*)(wr);
    h2v w1v = *(const h2v*)(wr + 512);
    h2v w2v = *(const h2v*)(wr + 1024);
    const float f0 = (float)w0[0],  f1 = (float)w0[1];
    const float f2 = (float)w1v[0], f3 = (float)w1v[1];
    const float f4 = (float)w2v[0], f5 = (float)w2v[1];
#pragma unroll
    for (int u = 0; u < 16; ++u) {
      const float d = dxu[u * 128 + k];
      acc[u][0] += d * f0; acc[u][1] += d * f1; acc[u][2] += d * f2;
      acc[u][3] += d * f3; acc[u][4] += d * f4; acc[u][5] += d * f5;
    }
  }
#pragma unroll
  for (int u = 0; u < 16; ++u) {
    unsigned int* o = DW12 + (size_t)(u0 + u) * 768 + tid * 3;
    HU p;
    p.h[0] = (_Float16)acc[u][0]; p.h[1] = (_Float16)acc[u][1]; o[0] = p.u;
    p.h[0] = (_Float16)acc[u][2]; p.h[1] = (_Float16)acc[u][3]; o[1] = p.u;
    p.h[0] = (_Float16)acc[u][4]; p.h[1] = (_Float16)acc[u][5]; o[2] = p.u;
  }
}

// One DW pipeline stage: consume bank CUR (4 t's), reload it 3 banks ahead.
#define DW_STEP(TB, CUR)                                                     \
  do {                                                                       \
    _Pragma("unroll")                                                        \
    for (int j = 0; j < 4; ++j) {                                            \
      const float a = asx[(TB) * 4 + j];                                     \
      HU p0, p1, p2; p0.u = CUR[j].x; p1.u = CUR[j].y; p2.u = CUR[j].z;      \
      aR0 += a * (float)p0.h[0]; aR1 += a * (float)p0.h[1];                  \
      aZ0 += a * (float)p1.h[0]; aZ1 += a * (float)p1.h[1];                  \
      aN0 += a * (float)p2.h[0]; aN1 += a * (float)p2.h[1];                  \
    }                                                                        \
    if ((TB) < 9) {                                                          \
      _Pragma("unroll")                                                      \
      for (int j = 0; j < 4; ++j)                                            \
        CUR[j] = *(const u32x3*)(dwp + (size_t)(((TB) + 3) * 4 + j) * 768);  \
    }                                                                        \
  } while (0)

// ---------------- main persistent scan kernel ----------------
__global__ __launch_bounds__(256, 1) void decoder_main(
    const float* __restrict__ xin, const float* __restrict__ h0,
    const float* __restrict__ W3, const float* __restrict__ b3,
    const float* __restrict__ Wfc, const float* __restrict__ bfc,
    const _Float16* __restrict__ Wzh, const float* __restrict__ bz,
    const _Float16* __restrict__ WcT, const float* __restrict__ bc,
    const _Float16* __restrict__ w2h, const unsigned int* __restrict__ DW12,
    _Float16* __restrict__ hgh, float* __restrict__ zg,
    unsigned int* __restrict__ bar, float* __restrict__ out)
{
  const int tid  = threadIdx.x;
  const int lane = tid & 63;
  const int wv   = tid >> 6;
  const int bid  = blockIdx.x;
  const int grp  = bid & 7;      // XCD-local heuristic (perf only)
  const int mem  = bid >> 3;     // 0..15
  const int b0   = grp * 16;
  const int myrow = b0 + mem;    // this block's row (ph2+ph3); == flag index
  const int cb   = mem * 128;    // ph1 column base (of 2048)
  const int myIdx = grp * 16 + mem;
  const int base16 = grp * 16;
  unsigned int* zflag = bar;           // [block]*32
  unsigned int* hflag = bar + 4096;    // [row]*32

  __shared__ __align__(16) _Float16 w2lds[48 * 512];  // 48 KiB
  __shared__ __align__(16) char hlds[16384];          // 16 KiB, swizzled h
  __shared__ float xlds[48 * 4];
  __shared__ float wfcs[512];
  __shared__ float es[48];
  __shared__ float asx[48];
  __shared__ float red[4];

  const int m = lane & 15, q = lane >> 4;

  // ---- ph1 persistent weights: 2 col-tiles of 16 per wave ----
  half8 wzf[2][16];
  int   ncol[2];
  float bzv[2];
#pragma unroll
  for (int t = 0; t < 2; ++t) {
    ncol[t] = cb + (wv * 2 + t) * 16 + m;
    const _Float16* wrow = Wzh + ncol[t] * 512 + q * 8;
#pragma unroll
    for (int ks = 0; ks < 16; ++ks)
      wzf[t][ks] = *(const half8*)(wrow + ks * 32);
    bzv[t] = bz[ncol[t]];
  }
  float w3r[8];
#pragma unroll
  for (int u = 0; u < 8; ++u) w3r[u] = W3[lane * 8 + u];
  const float b3v  = b3[0];
  const float bfcv = bfc[0];

  // ---- ph3 per-thread state: owns h-cols (c0, c0+1) of row myrow ----
  const int c0 = tid * 2;
  const float bcR0 = bc[c0],        bcR1 = bc[c0 + 1];
  const float bcZ0 = bc[512 + c0],  bcZ1 = bc[513 + c0];
  const float bcN0 = bc[1024 + c0], bcN1 = bc[1025 + c0];
  float wxR[3][2], wxZ[3][2], wxN[3][2];
#pragma unroll
  for (int j2 = 0; j2 < 3; ++j2) {
    const _Float16* wr = WcT + (128 + j2) * 1536 + c0;
    wxR[j2][0] = (float)wr[0];    wxR[j2][1] = (float)wr[1];
    wxZ[j2][0] = (float)wr[512];  wxZ[j2][1] = (float)wr[513];
    wxN[j2][0] = (float)wr[1024]; wxN[j2][1] = (float)wr[1025];
  }
  float hA = h0[myrow * 512 + c0];
  float hB = h0[myrow * 512 + c0 + 1];

  // ---- one-time LDS preload ----
  {
    const half8* w2src = (const half8*)(w2h + (size_t)myrow * 48 * 512);
    half8* w2dst = (half8*)w2lds;
    for (int i = tid; i < 3072; i += 256) w2dst[i] = w2src[i];
    for (int i = tid; i < 512; i += 256) wfcs[i] = Wfc[i];
    for (int i = tid; i < 144; i += 256) {
      const int t = i / 3, j2 = i - t * 3;
      xlds[t * 4 + j2] = xin[myrow * 144 + i];
    }
  }
  __syncthreads();

  const float* __restrict__ zrow = zg + (size_t)myrow * 2048;
  const unsigned int* __restrict__ dwp =
      DW12 + (size_t)myrow * 48 * 768 + (size_t)tid * 3;

  for (int step = 0; step < 48; ++step) {
    // ---- stage h: per-wave poll (4 rows each) + batched bypass loads ----
    {
      poll_ge(hflag + (size_t)(b0 + wv * 4 + (lane & 3)) * 32, lane < 4,
              (unsigned int)step);
      unsigned long long hv[8];
      const char* hbase = (const char*)hgh + (size_t)b0 * 1024 + (size_t)wv * 4096;
#pragma unroll
      for (int u = 0; u < 8; ++u)
        hv[u] = ld_u64(hbase + (size_t)(u * 64 + lane) * 8);
#pragma unroll
      for (int u = 0; u < 8; ++u) {
        const int n = wv * 512 + u * 64 + lane;
        const int row = n >> 7, b8 = (n & 127) * 8;
        *(unsigned long long*)(hlds + row * 1024 + (b8 ^ ((row & 7) << 4))) = hv[u];
      }
    }
    __syncthreads();

    // ---- ph1: z[16,2048] = h @ [W1|W_hh]^T + bz (MFMA, weights in regs) ----
    {
      half8 af[16];
      const char* hb = hlds + m * 1024;
      const int sw = (m & 7) << 4;
#pragma unroll
      for (int ks = 0; ks < 16; ++ks)
        af[ks] = *(const half8*)(hb + ((ks * 64 + q * 16) ^ sw));
#pragma unroll
      for (int t = 0; t < 2; ++t) {
        f32x4 acc = {bzv[t], bzv[t], bzv[t], bzv[t]};
#pragma unroll
        for (int ks = 0; ks < 16; ++ks)
          acc = __builtin_amdgcn_mfma_f32_16x16x32_f16(af[ks], wzf[t][ks], acc, 0, 0, 0);
#pragma unroll
        for (int r = 0; r < 4; ++r)
          st_f32(&zg[(size_t)(b0 + q * 4 + r) * 2048 + ncol[t]], acc[r]);
      }
    }
    __syncthreads();                       // drains vmcnt: z acked at MALL
    if (tid == 0) st_u32(&zflag[(size_t)myIdx * 32], (unsigned int)(step + 1));

    // ---- ph2: e -> softmax (needs only producers 0..3: w1 cols) ----
    {
      poll_ge(zflag + (size_t)(base16 + (lane & 3)) * 32, lane < 4,
              (unsigned int)(step + 1));
      float w1r[8];
#pragma unroll
      for (int u2 = 0; u2 < 4; ++u2) {
        U2 t2; t2.u = ld_u64(zrow + lane * 8 + u2 * 2);
        w1r[u2 * 2] = t2.f[0]; w1r[u2 * 2 + 1] = t2.f[1];
      }
      for (int tt = 0; tt < 12; ++tt) {
        const int t = wv * 12 + tt;
        half8 w2v = *(const half8*)(w2lds + t * 512 + lane * 8);
        float p = 0.f;
#pragma unroll
        for (int u = 0; u < 8; ++u)
          p += w3r[u] * fast_tanh(w1r[u] + (float)w2v[u]);
#pragma unroll
        for (int off = 32; off >= 1; off >>= 1) p += __shfl_xor(p, off);
        if (lane == 0) es[t] = p + b3v;
      }
      __syncthreads();
      if (wv == 0) {
        float e = (lane < 48) ? es[lane] : -1e30f;
        float mx = e;
#pragma unroll
        for (int off = 32; off >= 1; off >>= 1) mx = fmaxf(mx, __shfl_xor(mx, off));
        float pe = (lane < 48) ? fexp2((e - mx) * 1.4426950408889634f) : 0.f;
        float s = pe;
#pragma unroll
        for (int off = 32; off >= 1; off >>= 1) s += __shfl_xor(s, off);
        float a = pe * frcp(s);
        if (lane < 48) {
          asx[lane] = a;
          if (step == 47) out[128 + myrow * 48 + lane] = a;   // alpha (last step)
        }
      }
      __syncthreads();
    }

    // ---- ph3: gi = sum_t a_t*DW + x-part + bc ; GRU ; h_new (row-local) ----
    {
      // issue first 3 DW banks (plain cached loads; independent of z)
      u32x3 bA[4], bB[4], bC[4];
#pragma unroll
      for (int j = 0; j < 4; ++j) bA[j] = *(const u32x3*)(dwp + (size_t)(0 + j) * 768);
#pragma unroll
      for (int j = 0; j < 4; ++j) bB[j] = *(const u32x3*)(dwp + (size_t)(4 + j) * 768);
#pragma unroll
      for (int j = 0; j < 4; ++j) bC[j] = *(const u32x3*)(dwp + (size_t)(8 + j) * 768);
      // wait for gh producers (blocks 4..15), then issue gh loads (hidden
      // under the DW pipeline: first use is after the 48-term loop)
      poll_ge(zflag + (size_t)(base16 + 4 + (lane & 15)) * 32, lane < 12,
              (unsigned int)(step + 1));
      U2 tr, tz, tn2;
      tr.u  = ld_u64(zrow + 512 + c0);
      tz.u  = ld_u64(zrow + 1024 + c0);
      tn2.u = ld_u64(zrow + 1536 + c0);

      float aR0 = bcR0, aR1 = bcR1, aZ0 = bcZ0, aZ1 = bcZ1, aN0 = bcN0, aN1 = bcN1;
      DW_STEP(0, bA);  DW_STEP(1, bB);  DW_STEP(2, bC);
      DW_STEP(3, bA);  DW_STEP(4, bB);  DW_STEP(5, bC);
      DW_STEP(6, bA);  DW_STEP(7, bB);  DW_STEP(8, bC);
      DW_STEP(9, bA);  DW_STEP(10, bB); DW_STEP(11, bC);

      const float x0 = xlds[step * 4], x1 = xlds[step * 4 + 1], x2 = xlds[step * 4 + 2];
      aR0 += x0 * wxR[0][0] + x1 * wxR[1][0] + x2 * wxR[2][0];
      aR1 += x0 * wxR[0][1] + x1 * wxR[1][1] + x2 * wxR[2][1];
      aZ0 += x0 * wxZ[0][0] + x1 * wxZ[1][0] + x2 * wxZ[2][0];
      aZ1 += x0 * wxZ[0][1] + x1 * wxZ[1][1] + x2 * wxZ[2][1];
      aN0 += x0 * wxN[0][0] + x1 * wxN[1][0] + x2 * wxN[2][0];
      aN1 += x0 * wxN[0][1] + x1 * wxN[1][1] + x2 * wxN[2][1];

      const float r0 = fast_sigmoid(aR0 + tr.f[0]), r1 = fast_sigmoid(aR1 + tr.f[1]);
      const float z0 = fast_sigmoid(aZ0 + tz.f[0]), z1 = fast_sigmoid(aZ1 + tz.f[1]);
      const float n0 = fast_tanh(aN0 + r0 * tn2.f[0]), n1 = fast_tanh(aN1 + r1 * tn2.f[1]);
      hA = (1.f - z0) * n0 + z0 * hA;
      hB = (1.f - z1) * n1 + z1 * hB;
      HU hp; hp.h[0] = (_Float16)hA; hp.h[1] = (_Float16)hB;
      st_u32((unsigned int*)(hgh + myrow * 512 + c0), hp.u);   // h exchange
    }
    __syncthreads();                       // drains vmcnt: h acked at MALL
    if (tid == 0) st_u32(&hflag[(size_t)myrow * 32], (unsigned int)(step + 1));
  }

  // ---- epilogue: re[myrow] = h_f . Wfc + bfc (h in registers) ----
  {
    float p = hA * wfcs[c0] + hB * wfcs[c0 + 1];
#pragma unroll
    for (int off = 32; off >= 1; off >>= 1) p += __shfl_xor(p, off);
    if (lane == 0) red[wv] = p;
    __syncthreads();
    if (tid == 0) out[myrow] = red[0] + red[1] + red[2] + red[3] + bfcv;
  }
}

extern "C" void kernel_launch(void* const* d_in, const int* in_sizes, int n_in,
                              void* d_out, int out_size, void* d_ws, size_t ws_size,
                              hipStream_t stream) {
  (void)in_sizes; (void)n_in; (void)out_size; (void)ws_size;
  const float* dx  = (const float*)d_in[0];
  const float* xin = (const float*)d_in[1];
  const float* h0  = (const float*)d_in[2];
  const float* W1  = (const float*)d_in[3];
  const float* b1  = (const float*)d_in[4];
  const float* W2  = (const float*)d_in[5];
  const float* b2  = (const float*)d_in[6];
  const float* W3  = (const float*)d_in[7];
  const float* b3  = (const float*)d_in[8];
  const float* W4  = (const float*)d_in[9];
  const float* b4  = (const float*)d_in[10];
  const float* Wih = (const float*)d_in[11];
  const float* Whh = (const float*)d_in[12];
  const float* bih = (const float*)d_in[13];
  const float* bhh = (const float*)d_in[14];
  const float* Wfc = (const float*)d_in[15];
  const float* bfc = (const float*)d_in[16];

  char* ws = (char*)d_ws;
  unsigned int* bar = (unsigned int*)(ws + OFF_BAR);
  float*     bz  = (float*)(ws + OFF_BZ);
  float*     bc  = (float*)(ws + OFF_BC);
  _Float16*  Wzh = (_Float16*)(ws + OFF_WZ);
  _Float16*  WcT = (_Float16*)(ws + OFF_WCT);
  _Float16*  w2h = (_Float16*)(ws + OFF_W2H);
  _Float16*  hgh = (_Float16*)(ws + OFF_HGH);
  float*     zg  = (float*)(ws + OFF_ZG);
  unsigned int* DW12 = (unsigned int*)(ws + OFF_DW);

  prep_all<<<322, 256, 0, stream>>>(dx, h0, W1, Whh, b1, bhh, Wih, W4, b4, bih,
                                    W2, b2, hgh, Wzh, bz, bc, WcT, w2h, bar);
  prep_dw<<<384, 256, 0, stream>>>(dx, WcT, DW12);
  decoder_main<<<128, 256, 0, stream>>>(xin, h0, W3, b3, Wfc, bfc,
                                        Wzh, bz, WcT, bc, w2h, DW12,
                                        hgh, zg, bar, (float*)d_out);
}